// Round 1
// baseline (102.630 us; speedup 1.0000x reference)
//
#include <hip/hip_runtime.h>
#include <hip/hip_bf16.h>
#include <float.h>

// GraphSAGE fused kernel: masked-max neighbor aggregation + ReLU + concat + Linear.
// Shapes: adj [B=4,N=512,N], feat [B,N,C=128], W [2C=256,OUT=128], b [OUT].
// One block per (b,i) node; 128 threads = one channel / one output each.

#define Bsz 4
#define Nn  512
#define Cc  128
#define OUTn 128

__global__ __launch_bounds__(128) void sage_fused(
    const float* __restrict__ adj,
    const float* __restrict__ feat,
    const float* __restrict__ W,
    const float* __restrict__ bias,
    float* __restrict__ out)
{
    const int node = blockIdx.x;          // 0 .. B*N-1
    const int b = node >> 9;              // node / 512
    const int i = node & (Nn - 1);
    const int t = threadIdx.x;            // 0 .. 127

    __shared__ float s_adj[Nn];           // adjacency row (0/1 floats)
    __shared__ float s_comb[2 * Cc];      // [self(128) | neigh(128)]

    // Stage adjacency row into LDS (coalesced, 4 floats/thread)
    const float* adjrow = adj + (size_t)node * Nn;
    #pragma unroll
    for (int j = t; j < Nn; j += 128) s_adj[j] = adjrow[j];
    __syncthreads();

    // Masked max over neighbors: thread t owns channel t.
    // Branch is wave-uniform (s_adj[j] broadcast from LDS).
    const float* featb = feat + (size_t)b * Nn * Cc;
    float m = -FLT_MAX;
    for (int j = 0; j < Nn; ++j) {
        if (s_adj[j] > 0.0f) {
            m = fmaxf(m, featb[j * Cc + t]);
        }
    }
    // Reference: where(finfo.min finite -> kept) then relu => max(0, m) covers
    // both the no-neighbor case and ReLU.
    float neigh = fmaxf(m, 0.0f);
    float self  = featb[i * Cc + t];
    s_comb[t]        = self;
    s_comb[Cc + t]   = neigh;
    __syncthreads();

    // out[node, t] = sum_c s_comb[c] * W[c, t] + bias[t]
    float acc = bias[t];
    #pragma unroll 8
    for (int c = 0; c < 2 * Cc; ++c) {
        acc += s_comb[c] * W[c * OUTn + t];
    }
    out[(size_t)node * OUTn + t] = acc;
}

extern "C" void kernel_launch(void* const* d_in, const int* in_sizes, int n_in,
                              void* d_out, int out_size, void* d_ws, size_t ws_size,
                              hipStream_t stream) {
    const float* adj  = (const float*)d_in[0];
    const float* feat = (const float*)d_in[1];
    const float* W    = (const float*)d_in[2];
    const float* bias = (const float*)d_in[3];
    float* out = (float*)d_out;

    dim3 grid(Bsz * Nn);
    dim3 block(128);
    sage_fused<<<grid, block, 0, stream>>>(adj, feat, W, bias, out);
}

// Round 3
// 73.571 us; speedup vs baseline: 1.3950x; 1.3950x over previous
//
#include <hip/hip_runtime.h>
#include <hip/hip_bf16.h>
#include <float.h>

// GraphSAGE: masked-max aggregation + ReLU + concat + Linear(256->128).
// B=4, N=512, C=128, OUT=128.
//
// Pipeline (3 kernels, same stream):
//   1. prep_wt : W fp32 [256][128] -> Wt bf16 [128][256]  (ws + 1MB)
//   2. sage_agg: ballot-compacted neighbor max -> comb bf16 [2048][256] (ws)
//   3. sage_gemm: MFMA 16x16x32 bf16, C = comb @ W + bias -> out fp32
//
// R2 bug fix: sage_gemm grid was 128 blocks (stray /2) -> half the 1024
// tiles unwritten (absmax 7.375 = max|ref| over missing half). Now 256.

#define Bsz 4
#define Nn  512
#define Cc  128
#define OUTn 128
#define NNODES (Bsz * Nn)   // 2048
#define KK (2 * Cc)         // 256

typedef __bf16 bf16x8 __attribute__((ext_vector_type(8)));
typedef float  f32x4  __attribute__((ext_vector_type(4)));

static __device__ __forceinline__ unsigned short f2bf(float x) {
    __hip_bfloat16 h = __float2bfloat16(x);
    return *reinterpret_cast<unsigned short*>(&h);
}

// ---- kernel 1: W [256][128] fp32 -> Wt [128][256] bf16 -------------------
__global__ __launch_bounds__(256) void prep_wt(
    const float* __restrict__ W, unsigned short* __restrict__ Wt)
{
    int idx = blockIdx.x * 256 + threadIdx.x;   // 0..32767, coalesced read
    int kk = idx >> 7;          // 0..255
    int n  = idx & 127;         // 0..127
    float v = W[idx];           // W[kk][n]
    Wt[n * KK + kk] = f2bf(v);  // scattered 2B store; tiny kernel
}

// ---- kernel 2: aggregation -----------------------------------------------
// block = 256 threads = 4 waves; wave w handles node blockIdx.x*4 + w.
// Lane l owns channels 2l and 2l+1 (float2 loads).
__global__ __launch_bounds__(256) void sage_agg(
    const float* __restrict__ adj,
    const float* __restrict__ feat,
    unsigned short* __restrict__ comb)   // [2048][256] bf16: [self(128)|neigh(128)]
{
    const int w = threadIdx.x >> 6;
    const int l = threadIdx.x & 63;
    const int node = blockIdx.x * 4 + w;
    const int b = node >> 9;
    const int i = node & (Nn - 1);

    __shared__ unsigned short nbr[4][Nn];

    const float* adjrow = adj + (size_t)node * Nn;
    const float2* f2 = (const float2*)(feat + (size_t)b * Nn * Cc);

    // Ballot-compact the adjacency row into a per-wave index list (no atomics).
    int cnt = 0;
    #pragma unroll
    for (int ch = 0; ch < Nn / 64; ++ch) {
        float a = adjrow[ch * 64 + l];
        unsigned long long mask = __ballot(a > 0.0f);
        int pos = __popcll(mask & ((1ull << l) - 1ull));
        if (a > 0.0f) nbr[w][cnt + pos] = (unsigned short)(ch * 64 + l);
        cnt += __popcll(mask);
    }
    // Cross-lane LDS handoff: make the writes visible before the reads.
    // (Uniform control flow — all 4 waves reach this.)
    __syncthreads();

    float m0 = -FLT_MAX, m1 = -FLT_MAX;
    int k = 0;
    for (; k + 4 <= cnt; k += 4) {
        int j0 = nbr[w][k + 0], j1 = nbr[w][k + 1];
        int j2 = nbr[w][k + 2], j3 = nbr[w][k + 3];
        float2 v0 = f2[j0 * 64 + l];
        float2 v1 = f2[j1 * 64 + l];
        float2 v2 = f2[j2 * 64 + l];
        float2 v3 = f2[j3 * 64 + l];
        m0 = fmaxf(m0, fmaxf(fmaxf(v0.x, v1.x), fmaxf(v2.x, v3.x)));
        m1 = fmaxf(m1, fmaxf(fmaxf(v0.y, v1.y), fmaxf(v2.y, v3.y)));
    }
    for (; k < cnt; ++k) {
        int j = nbr[w][k];
        float2 v = f2[j * 64 + l];
        m0 = fmaxf(m0, v.x);
        m1 = fmaxf(m1, v.y);
    }

    // relu(max) covers the no-neighbor case (-FLT_MAX -> 0), matching the
    // reference's where(isfinite)->relu since finfo.min is finite.
    float n0 = fmaxf(m0, 0.0f), n1 = fmaxf(m1, 0.0f);
    float2 s = f2[i * 64 + l];

    ushort2* crow = (ushort2*)(comb + (size_t)node * KK);
    ushort2 sv; sv.x = f2bf(s.x); sv.y = f2bf(s.y);
    ushort2 nv; nv.x = f2bf(n0);  nv.y = f2bf(n1);
    crow[l]      = sv;   // self   channels [2l, 2l+1]
    crow[64 + l] = nv;   // neigh  channels [128+2l, 128+2l+1]
}

// ---- kernel 3: GEMM  out[2048][128] = comb[2048][256] @ W[256][128] + b --
// One 16x16 tile per wave, K=256 in 8 mfma_f32_16x16x32_bf16 steps.
// A-frag: lane holds A[m = lane&15][k = (lane>>4)*8 + j], contiguous 16B.
// B-frag: lane holds B[k = (lane>>4)*8 + j][n = lane&15] -> contiguous in Wt[n][k].
// C/D:    col = lane&15, row = (lane>>4)*4 + reg   [measured m89/m91]
__global__ __launch_bounds__(256) void sage_gemm(
    const __bf16* __restrict__ A,    // comb
    const __bf16* __restrict__ Bt,   // Wt [128][256]
    const float* __restrict__ bias,
    float* __restrict__ out)
{
    const int wave = threadIdx.x >> 6;
    const int lane = threadIdx.x & 63;
    const int tile = blockIdx.x * 4 + wave;   // 0..1023
    const int nt = tile & 7;                  // 8 n-tiles
    const int mt = tile >> 3;                 // 128 m-tiles

    const int frow = lane & 15;
    const int koff = (lane >> 4) * 8;

    const __bf16* pa = A  + (size_t)(mt * 16 + frow) * KK + koff;
    const __bf16* pb = Bt + (size_t)(nt * 16 + frow) * KK + koff;

    f32x4 acc = {0.f, 0.f, 0.f, 0.f};
    #pragma unroll
    for (int ks = 0; ks < KK / 32; ++ks) {
        bf16x8 af = *(const bf16x8*)(pa + ks * 32);
        bf16x8 bf = *(const bf16x8*)(pb + ks * 32);
        acc = __builtin_amdgcn_mfma_f32_16x16x32_bf16(af, bf, acc, 0, 0, 0);
    }

    const int col = lane & 15;            // n within tile
    const int r0  = (lane >> 4) * 4;      // m within tile
    const float bv = bias[nt * 16 + col];
    #pragma unroll
    for (int r = 0; r < 4; ++r) {
        out[(size_t)(mt * 16 + r0 + r) * OUTn + nt * 16 + col] = acc[r] + bv;
    }
}

extern "C" void kernel_launch(void* const* d_in, const int* in_sizes, int n_in,
                              void* d_out, int out_size, void* d_ws, size_t ws_size,
                              hipStream_t stream) {
    const float* adj  = (const float*)d_in[0];
    const float* feat = (const float*)d_in[1];
    const float* W    = (const float*)d_in[2];
    const float* bias = (const float*)d_in[3];
    float* out = (float*)d_out;

    unsigned short* comb = (unsigned short*)d_ws;                    // 2048*256*2 = 1 MB
    unsigned short* Wt   = comb + (size_t)NNODES * KK;               // 128*256*2 = 64 KB

    prep_wt  <<<dim3(KK * OUTn / 256), dim3(256), 0, stream>>>(W, Wt);
    sage_agg <<<dim3(NNODES / 4),      dim3(256), 0, stream>>>(adj, feat, comb);
    // 1024 tiles (128 mt x 8 nt), 4 waves/block -> 256 blocks.
    sage_gemm<<<dim3(NNODES / 16 * (OUTn / 16) / 4), dim3(256), 0, stream>>>(
        (const __bf16*)comb, (const __bf16*)Wt, bias, out);
}

// Round 4
// 68.529 us; speedup vs baseline: 1.4976x; 1.0736x over previous
//
#include <hip/hip_runtime.h>
#include <hip/hip_bf16.h>
#include <float.h>

// GraphSAGE: masked-max aggregation + ReLU + concat + Linear(256->128).
// B=4, N=512, C=128, OUT=128.
//
// R4: two kernels.
//  1. sage_agg : 1 block (4 waves) per node; each wave ballot-compacts and
//     max-scans a quarter of the adjacency row; LDS combine. 32 waves/CU.
//  2. sage_gemm: MFMA 16x16x32 bf16; B-frags built on the fly from fp32 W
//     (L2-hot), A-frags from bf16 comb in ws. prep_wt eliminated.

#define Bsz 4
#define Nn  512
#define Cc  128
#define OUTn 128
#define NNODES (Bsz * Nn)   // 2048
#define KK (2 * Cc)         // 256

typedef __bf16 bf16x8 __attribute__((ext_vector_type(8)));
typedef float  f32x4  __attribute__((ext_vector_type(4)));

static __device__ __forceinline__ unsigned short f2bf(float x) {
    __hip_bfloat16 h = __float2bfloat16(x);
    return *reinterpret_cast<unsigned short*>(&h);
}
static __device__ __forceinline__ __bf16 f2bf16(float x) {
    unsigned short u = f2bf(x);
    return *reinterpret_cast<__bf16*>(&u);
}

// ---- kernel 1: aggregation -----------------------------------------------
// Block = 256 threads = 4 waves, one node per block.
// Wave w owns neighbor range [w*128, w*128+128); lane l owns channels 2l,2l+1.
__global__ __launch_bounds__(256) void sage_agg(
    const float* __restrict__ adj,
    const float* __restrict__ feat,
    unsigned short* __restrict__ comb)   // [2048][256] bf16: [self(128)|neigh(128)]
{
    const int w = threadIdx.x >> 6;
    const int l = threadIdx.x & 63;
    const int node = blockIdx.x;
    const int b = node >> 9;
    const int i = node & (Nn - 1);

    __shared__ unsigned short nbr[4][128];   // per-wave compacted indices
    __shared__ float2 pmax[4][64];           // per-wave partial max (ch pairs)

    const float* adjrow = adj + (size_t)node * Nn;
    const float2* f2 = (const float2*)(feat + (size_t)b * Nn * Cc);

    // Ballot-compact this wave's quarter of the adjacency row (2 chunks).
    int cnt = 0;
    #pragma unroll
    for (int ch = 0; ch < 2; ++ch) {
        int j = w * 128 + ch * 64 + l;
        float a = adjrow[j];
        unsigned long long mask = __ballot(a > 0.0f);
        int pos = __popcll(mask & ((1ull << l) - 1ull));
        if (a > 0.0f) nbr[w][cnt + pos] = (unsigned short)j;
        cnt += __popcll(mask);
    }
    // Same-wave DS write->read: HW lgkmcnt ordering guarantees visibility.

    float m0 = -FLT_MAX, m1 = -FLT_MAX;
    int k = 0;
    for (; k + 4 <= cnt; k += 4) {
        int j0 = nbr[w][k + 0], j1 = nbr[w][k + 1];
        int j2 = nbr[w][k + 2], j3 = nbr[w][k + 3];
        float2 v0 = f2[j0 * 64 + l];
        float2 v1 = f2[j1 * 64 + l];
        float2 v2 = f2[j2 * 64 + l];
        float2 v3 = f2[j3 * 64 + l];
        m0 = fmaxf(m0, fmaxf(fmaxf(v0.x, v1.x), fmaxf(v2.x, v3.x)));
        m1 = fmaxf(m1, fmaxf(fmaxf(v0.y, v1.y), fmaxf(v2.y, v3.y)));
    }
    for (; k < cnt; ++k) {
        int j = nbr[w][k];
        float2 v = f2[j * 64 + l];
        m0 = fmaxf(m0, v.x);
        m1 = fmaxf(m1, v.y);
    }
    pmax[w][l] = make_float2(m0, m1);
    __syncthreads();

    // Wave 0 combines the 4 partials, applies relu, loads self, stores row.
    if (w == 0) {
        float2 p0 = pmax[0][l], p1 = pmax[1][l], p2 = pmax[2][l], p3 = pmax[3][l];
        float n0 = fmaxf(fmaxf(p0.x, p1.x), fmaxf(p2.x, p3.x));
        float n1 = fmaxf(fmaxf(p0.y, p1.y), fmaxf(p2.y, p3.y));
        // relu(max) covers no-neighbor (-FLT_MAX) too, matching the reference
        // (finfo.min is finite, so its isfinite-guard never fires).
        n0 = fmaxf(n0, 0.0f);
        n1 = fmaxf(n1, 0.0f);
        float2 s = f2[i * 64 + l];

        ushort2* crow = (ushort2*)(comb + (size_t)node * KK);
        ushort2 sv; sv.x = f2bf(s.x); sv.y = f2bf(s.y);
        ushort2 nv; nv.x = f2bf(n0);  nv.y = f2bf(n1);
        crow[l]      = sv;   // self  channels [2l, 2l+1]
        crow[64 + l] = nv;   // neigh channels [128+2l, 128+2l+1]
    }
}

// ---- kernel 2: GEMM  out[2048][128] = comb[2048][256] @ W[256][128] + b --
// One 16x16 tile per wave, K=256 in 8 mfma_f32_16x16x32_bf16 steps.
// A-frag: lane holds A[m = lane&15][k = koff+j], contiguous 16B bf16 load.
// B-frag: lane holds B[k = koff+j][n = lane&15], built from fp32 W on the fly
//         (8 dword loads + cvt; W is 128KB, L2-hot, reused by all waves).
// C/D:    col = lane&15, row = (lane>>4)*4 + reg   [measured m89/m91]
__global__ __launch_bounds__(256) void sage_gemm(
    const __bf16* __restrict__ A,    // comb bf16 [2048][256]
    const float* __restrict__ W,     // fp32 [256][128]
    const float* __restrict__ bias,
    float* __restrict__ out)
{
    const int wave = threadIdx.x >> 6;
    const int lane = threadIdx.x & 63;
    const int tile = blockIdx.x * 4 + wave;   // 0..1023
    const int nt = tile & 7;                  // 8 n-tiles
    const int mt = tile >> 3;                 // 128 m-tiles

    const int frow = lane & 15;
    const int koff = (lane >> 4) * 8;

    const __bf16* pa = A + (size_t)(mt * 16 + frow) * KK + koff;
    const float*  wp = W + nt * 16 + frow;    // column (n) base; stride 128 over k

    f32x4 acc = {0.f, 0.f, 0.f, 0.f};
    #pragma unroll
    for (int ks = 0; ks < KK / 32; ++ks) {
        bf16x8 af = *(const bf16x8*)(pa + ks * 32);
        bf16x8 bf;
        #pragma unroll
        for (int j = 0; j < 8; ++j) {
            bf[j] = f2bf16(wp[(size_t)(ks * 32 + koff + j) * OUTn]);
        }
        acc = __builtin_amdgcn_mfma_f32_16x16x32_bf16(af, bf, acc, 0, 0, 0);
    }

    const int col = lane & 15;            // n within tile
    const int r0  = (lane >> 4) * 4;      // m within tile
    const float bv = bias[nt * 16 + col];
    #pragma unroll
    for (int r = 0; r < 4; ++r) {
        out[(size_t)(mt * 16 + r0 + r) * OUTn + nt * 16 + col] = acc[r] + bv;
    }
}

extern "C" void kernel_launch(void* const* d_in, const int* in_sizes, int n_in,
                              void* d_out, int out_size, void* d_ws, size_t ws_size,
                              hipStream_t stream) {
    const float* adj  = (const float*)d_in[0];
    const float* feat = (const float*)d_in[1];
    const float* W    = (const float*)d_in[2];
    const float* bias = (const float*)d_in[3];
    float* out = (float*)d_out;

    unsigned short* comb = (unsigned short*)d_ws;   // 2048*256*2 = 1 MB

    sage_agg <<<dim3(NNODES), dim3(256), 0, stream>>>(adj, feat, comb);
    // 1024 tiles (128 mt x 8 nt), 4 waves/block -> 256 blocks.
    sage_gemm<<<dim3(NNODES / 16 * (OUTn / 16) / 4), dim3(256), 0, stream>>>(
        (const __bf16*)comb, W, bias, out);
}